// Round 9
// baseline (155.900 us; speedup 1.0000x reference)
//
#include <hip/hip_runtime.h>
#include <math.h>

#define T_LEN 2097152
#define K 8
#define D 4
#define CHUNK 8
#define TPB 256
#define NBLK (T_LEN / (CHUNK * TPB))  // 1024 blocks -> 4/CU (LDS-bound), 16 waves/CU
#define MSTRIDE 65                    // LDS matrix stride (floats)

// ws layout (floats): [0..63] Tr; [64..71] a; [72..103] b; [104..135] c; [136..143] alpha0
// [256..) bp (NBLK*64 floats), then bs (NBLK ints), then counter (1 int)

__device__ __forceinline__ void renorm_mat(float P[K][K], int& shift) {
    float mx = 0.f;
#pragma unroll
    for (int i = 0; i < K; ++i)
#pragma unroll
        for (int j = 0; j < K; ++j) mx = fmaxf(mx, P[i][j]);
    int ex = (__float_as_int(mx) >> 23) & 255;
    float scale = __int_as_float((254 - ex) << 23); // 2^(127-ex)
    shift += ex - 127;
#pragma unroll
    for (int i = 0; i < K; ++i)
#pragma unroll
        for (int j = 0; j < K; ++j) P[i][j] *= scale;
}

__device__ __forceinline__ void mat_combine(const float L[K][K], const float R[K][K], float C[K][K]) {
#pragma unroll
    for (int i = 0; i < K; ++i) {
        float q[K];
#pragma unroll
        for (int j = 0; j < K; ++j) q[j] = L[i][0] * R[0][j];
#pragma unroll
        for (int k = 1; k < K; ++k)
#pragma unroll
            for (int j = 0; j < K; ++j) q[j] = fmaf(L[i][k], R[k][j], q[j]);
#pragma unroll
        for (int j = 0; j < K; ++j) C[i][j] = q[j];
    }
}

__device__ __forceinline__ void combine_stream(const float* __restrict__ Lp,
                                               const float* __restrict__ Rp,
                                               float C[K][K]) {
#pragma unroll
    for (int k = 0; k < K; ++k) {
        float Lc[K], Rr[K];
#pragma unroll
        for (int i = 0; i < K; ++i) Lc[i] = Lp[i * 8 + k];
#pragma unroll
        for (int j = 0; j < K; ++j) Rr[j] = Rp[k * 8 + j];
        if (k == 0) {
#pragma unroll
            for (int i = 0; i < K; ++i)
#pragma unroll
                for (int j = 0; j < K; ++j) C[i][j] = Lc[i] * Rr[j];
        } else {
#pragma unroll
            for (int i = 0; i < K; ++i)
#pragma unroll
                for (int j = 0; j < K; ++j) C[i][j] = fmaf(Lc[i], Rr[j], C[i][j]);
        }
    }
}

// Hybrid tree over 256 time-ordered per-thread matrices (lm: 128 slots, stride 65).
// Level 1 masked through LDS; levels 2..8 packed (one combine per lane).
__device__ __forceinline__ void hybrid_tree(float P[K][K], int& shift, float* lm, int* lsh) {
    const int t = threadIdx.x;
    if ((t & 1) == 0) {
#pragma unroll
        for (int i = 0; i < K; ++i)
#pragma unroll
            for (int j = 0; j < K; ++j) lm[(t >> 1) * MSTRIDE + i * 8 + j] = P[i][j];
        lsh[t >> 1] = shift;
    }
    __syncthreads();
    if (t & 1) {
        float L[K][K];
#pragma unroll
        for (int i = 0; i < K; ++i)
#pragma unroll
            for (int k = 0; k < K; ++k) L[i][k] = lm[(t >> 1) * MSTRIDE + i * 8 + k];
        float C[K][K];
        mat_combine(L, P, C); // L earlier in time
        int ns = shift + lsh[t >> 1];
        renorm_mat(C, ns);
#pragma unroll
        for (int i = 0; i < K; ++i)
#pragma unroll
            for (int j = 0; j < K; ++j) lm[(t >> 1) * MSTRIDE + i * 8 + j] = C[i][j];
        lsh[t >> 1] = ns;
    }
    __syncthreads();
    const int lane = t & 63, w = t >> 6;
#pragma unroll 1
    for (int r = 1; r <= 7; ++r) {
        const int c = 64 >> (r - 1);
        const int S = 1 << (r - 1);
        const int aw = r & 1;
        if (w == aw && lane < c) {
            const int li = (2 * lane) * S, ri = li + S;
            float C[K][K];
            combine_stream(&lm[li * MSTRIDE], &lm[ri * MSTRIDE], C);
            int ns = lsh[li] + lsh[ri];
            renorm_mat(C, ns);
#pragma unroll
            for (int i = 0; i < K; ++i)
#pragma unroll
                for (int j = 0; j < K; ++j) lm[li * MSTRIDE + i * 8 + j] = C[i][j];
            lsh[li] = ns;
        }
        __syncthreads();
    }
}

// 64-thread parallel setup (keeps main's consts uniform -> SGPR)
__global__ void hmm_setup(const float* __restrict__ x,
                          const float* __restrict__ ut,
                          const float* __restrict__ up,
                          const float* __restrict__ mn,
                          const float* __restrict__ lsd,
                          float* __restrict__ ws) {
    const int lane = threadIdx.x;
    const float L2PI = 1.83787706640934548356f;
    const float LOG2E = 1.44269504088896340736f;

    float v = ut[lane];
    float m = v;
    m = fmaxf(m, __shfl_xor(m, 1));
    m = fmaxf(m, __shfl_xor(m, 2));
    m = fmaxf(m, __shfl_xor(m, 4));
    float e = expf(v - m);
    float s = e;
    s += __shfl_xor(s, 1); s += __shfl_xor(s, 2); s += __shfl_xor(s, 4);
    ws[lane] = e / s;

    float pv = up[lane & 7];
    float pm = pv;
    pm = fmaxf(pm, __shfl_xor(pm, 1));
    pm = fmaxf(pm, __shfl_xor(pm, 2));
    pm = fmaxf(pm, __shfl_xor(pm, 4));
    float pe = expf(pv - pm);
    float ps = pe;
    ps += __shfl_xor(ps, 1); ps += __shfl_xor(ps, 2); ps += __shfl_xor(ps, 4);
    float pival = pe / ps;

    int k = (lane & 31) >> 2, d = lane & 3;
    float lv = lsd[k * D + d];
    float mu = mn[k * D + d];
    float iv = expf(-2.f * lv);
    float bn = mu * iv;
    float cn = -0.5f * iv;
    float aterm = -0.5f * L2PI - lv - 0.5f * mu * mu * iv;
    float ak = aterm;
    ak += __shfl_xor(ak, 1); ak += __shfl_xor(ak, 2);
    if (lane < 32) {
        ws[72 + lane]  = bn * LOG2E;
        ws[104 + lane] = cn * LOG2E;
        if (d == 0) ws[64 + k] = ak * LOG2E;
    }

    float xd = x[d];
    float part = (cn * xd + bn) * xd + aterm;
    part += __shfl_xor(part, 1); part += __shfl_xor(part, 2);
    float pik = __shfl(pival, k);
    if (lane < 32 && d == 0) ws[136 + k] = pik * expf(part);
}

__global__ __launch_bounds__(TPB) void hmm_main(const float* __restrict__ x,
                                                const float* __restrict__ cst,
                                                float* __restrict__ bp,
                                                int* __restrict__ bs,
                                                int* __restrict__ counter,
                                                float* __restrict__ out) {
    // 8320 floats: scan phase = per-wave x stage (4 x 2080); tree phase = 128 mats x 65
    __shared__ float smem[8320];
    __shared__ int lsh[128];
    __shared__ int lastFlag;
    const int tid = blockIdx.x * TPB + threadIdx.x;
    const int w = threadIdx.x >> 6, l = threadIdx.x & 63;

    // uniform constants -> scalar loads
    float Tr[K][K];
#pragma unroll
    for (int i = 0; i < K; ++i)
#pragma unroll
        for (int j = 0; j < K; ++j) Tr[i][j] = cst[i * K + j];
    float ca[K], cb[K][D], cc[K][D];
#pragma unroll
    for (int k = 0; k < K; ++k) {
        ca[k] = cst[64 + k];
#pragma unroll
        for (int d = 0; d < D; ++d) {
            cb[k][d] = cst[72 + k * D + d];
            cc[k][d] = cst[104 + k * D + d];
        }
    }

    // ---- coalesced staging: wave's 8KB x-region -> LDS, transposed [step*4+comp][chunk]
    float* st = smem + w * 2080; // 32 rows x 65 floats
    {
        const float4* gx = reinterpret_cast<const float4*>(x) +
                           ((size_t)blockIdx.x * TPB + (size_t)w * 64) * CHUNK;
        float4 v[8];
#pragma unroll
        for (int it = 0; it < 8; ++it) v[it] = gx[it * 64 + l];
        const int a = l >> 3, b = l & 7;
#pragma unroll
        for (int it = 0; it < 8; ++it) {
            const int c = it * 8 + a; // chunk-local 0..63
            st[(b * 4 + 0) * 65 + c] = v[it].x;
            st[(b * 4 + 1) * 65 + c] = v[it].y;
            st[(b * 4 + 2) * 65 + c] = v[it].z;
            st[(b * 4 + 3) * 65 + c] = v[it].w;
        }
    }
    // wave-local producer/consumer: same wave wrote, same wave reads -> no barrier

    float P[K][K];
    int shift = 0;
    if (tid == 0) {
#pragma unroll
        for (int i = 0; i < K; ++i)
#pragma unroll
            for (int j = 0; j < K; ++j) P[i][j] = (i == j) ? cst[136 + i] : 0.0f;
    } else {
        float x0 = st[0 * 65 + l], x1 = st[1 * 65 + l], x2 = st[2 * 65 + l], x3 = st[3 * 65 + l];
        float e[K];
#pragma unroll
        for (int j = 0; j < K; ++j) {
            float em = ca[j];
            em = fmaf(fmaf(cc[j][0], x0, cb[j][0]), x0, em);
            em = fmaf(fmaf(cc[j][1], x1, cb[j][1]), x1, em);
            em = fmaf(fmaf(cc[j][2], x2, cb[j][2]), x2, em);
            em = fmaf(fmaf(cc[j][3], x3, cb[j][3]), x3, em);
            e[j] = exp2f(em);
        }
#pragma unroll
        for (int i = 0; i < K; ++i)
#pragma unroll
            for (int j = 0; j < K; ++j) P[i][j] = Tr[i][j] * e[j];
    }

    // scan: P <- (P*Tr) .col e_t ; pow2 renorm every 2nd step folded into next e
    float fcarry = 0.0f;
    int icarry = 0;
#pragma unroll 1
    for (int t = 1; t < CHUNK; ++t) {
        float x0 = st[(t * 4 + 0) * 65 + l], x1 = st[(t * 4 + 1) * 65 + l];
        float x2 = st[(t * 4 + 2) * 65 + l], x3 = st[(t * 4 + 3) * 65 + l];
        float e[K];
#pragma unroll
        for (int j = 0; j < K; ++j) {
            float em = ca[j];
            em = fmaf(fmaf(cc[j][0], x0, cb[j][0]), x0, em);
            em = fmaf(fmaf(cc[j][1], x1, cb[j][1]), x1, em);
            em = fmaf(fmaf(cc[j][2], x2, cb[j][2]), x2, em);
            em = fmaf(fmaf(cc[j][3], x3, cb[j][3]), x3, em);
            e[j] = exp2f(em + fcarry);
        }
        shift -= icarry;
#pragma unroll
        for (int i = 0; i < K; ++i) {
            float q[K];
#pragma unroll
            for (int j = 0; j < K; ++j) q[j] = P[i][0] * Tr[0][j];
#pragma unroll
            for (int k = 1; k < K; ++k)
#pragma unroll
                for (int j = 0; j < K; ++j) q[j] = fmaf(P[i][k], Tr[k][j], q[j]);
#pragma unroll
            for (int j = 0; j < K; ++j) P[i][j] = q[j] * e[j];
        }
        if ((t & 1) == 0) {
            float mx = 0.f;
#pragma unroll
            for (int i = 0; i < K; ++i)
#pragma unroll
                for (int j = 0; j < K; ++j) mx = fmaxf(mx, P[i][j]);
            int ex = (__float_as_int(mx) >> 23) & 255;
            icarry = 127 - ex;
            fcarry = (float)icarry;
        } else {
            icarry = 0;
            fcarry = 0.0f;
        }
    }
    renorm_mat(P, shift);

    __syncthreads(); // all waves done reading staged x before tree overwrites smem
    hybrid_tree(P, shift, smem, lsh);

    // block product -> global; last block to finish reduces all blocks
    if (threadIdx.x == 0) {
        float4* o4 = reinterpret_cast<float4*>(bp + (size_t)blockIdx.x * 64);
        const float4* l4 = reinterpret_cast<const float4*>(smem);
#pragma unroll
        for (int q = 0; q < 16; ++q) o4[q] = l4[q];
        bs[blockIdx.x] = lsh[0];
        __threadfence(); // release
        int old = atomicAdd(counter, 1);
        lastFlag = (old == NBLK - 1) ? 1 : 0;
    }
    __syncthreads();
    if (!lastFlag) return;
    __threadfence(); // acquire

    // ---- final phase (last block only): 1024 mats -> 256 serial(4) -> tree -> out
    {
        const int t = threadIdx.x;
        const int base = t * 4;
        float Pf[K][K];
        {
            const float4* p4 = reinterpret_cast<const float4*>(bp + (size_t)base * 64);
            float4* dst = reinterpret_cast<float4*>(&Pf[0][0]);
#pragma unroll
            for (int q = 0; q < 16; ++q) dst[q] = p4[q];
        }
        int sh = bs[base];
#pragma unroll 1
        for (int r = 1; r < 4; ++r) {
            const float* Rp = bp + (size_t)(base + r) * 64;
            float C[K][K];
            combine_stream(&Pf[0][0], Rp, C);
            sh += bs[base + r];
            renorm_mat(C, sh);
#pragma unroll
            for (int i = 0; i < K; ++i)
#pragma unroll
                for (int j = 0; j < K; ++j) Pf[i][j] = C[i][j];
        }
        __syncthreads(); // smem free for tree reuse
        hybrid_tree(Pf, sh, smem, lsh);
    }
    if (threadIdx.x == 0) {
        double s = 0.0;
#pragma unroll
        for (int i = 0; i < K; ++i)
#pragma unroll
            for (int j = 0; j < K; ++j) s += (double)smem[i * 8 + j];
        out[0] = (float)(log(s) + (double)lsh[0] * 0.69314718055994530942);
    }
}

extern "C" void kernel_launch(void* const* d_in, const int* in_sizes, int n_in,
                              void* d_out, int out_size, void* d_ws, size_t ws_size,
                              hipStream_t stream) {
    (void)in_sizes; (void)n_in; (void)out_size; (void)ws_size;
    const float* x  = (const float*)d_in[0];
    const float* ut = (const float*)d_in[1];
    const float* up = (const float*)d_in[2];
    const float* mn = (const float*)d_in[3];
    const float* ls = (const float*)d_in[4];
    float* ws  = (float*)d_ws;
    float* out = (float*)d_out;
    float* bp  = ws + 256;
    int* bs    = (int*)(ws + 256 + (size_t)NBLK * 64);
    int* cnt   = bs + NBLK;

    hmm_setup<<<1, 64, 0, stream>>>(x, ut, up, mn, ls, ws);
    hipMemsetAsync((void*)cnt, 0, sizeof(int), stream);
    hmm_main<<<NBLK, TPB, 0, stream>>>(x, ws, bp, bs, cnt, out);
}